// Round 1
// baseline (3843.595 us; speedup 1.0000x reference)
//
#include <hip/hip_runtime.h>
#include <math.h>

#define N_NODES 100000
#define N_EDGES 600000
#define N_GRAPHS 512
#define D 128

// ---------------- zero ----------------
__global__ __launch_bounds__(256) void zero_kernel(float* __restrict__ p, int n) {
    int i = blockIdx.x * 256 + threadIdx.x;
    if (i < n) p[i] = 0.0f;
}

// ---------------- edge scatter (segment-sum of h[src] into msg[dst]) ----------------
// thread = (edge, 4-float chunk). 32 chunks per edge (D=128).
__global__ __launch_bounds__(256) void scatter_kernel(const float* __restrict__ h,
                                                      const int* __restrict__ src,
                                                      const int* __restrict__ dst,
                                                      float* __restrict__ msg,
                                                      float* __restrict__ cnt) {
    int idx = blockIdx.x * 256 + threadIdx.x;      // < E*32 = 19.2M
    int e = idx >> 5;
    int q = idx & 31;
    if (e >= N_EDGES) return;
    int s = src[e];
    int d = dst[e];
    const float4 v = ((const float4*)(h + (size_t)s * D))[q];
    float* mrow = msg + (size_t)d * D + q * 4;
    atomicAdd(mrow + 0, v.x);
    atomicAdd(mrow + 1, v.y);
    atomicAdd(mrow + 2, v.z);
    atomicAdd(mrow + 3, v.w);
    if (q == 0) atomicAdd(cnt + d, 1.0f);
}

// ---------------- fused mean + dual GEMM + bias + relu ----------------
// out[r][c] = relu( sum_k mean[r][k]*Wl[k][c] + h[r][k]*Wr[k][c] + b[c] )
// block: 128 threads (c = threadIdx.x), ROWS rows per block.
// out may alias msg: each block reads its own rows into LDS before writing.
#define ROWS 8
__global__ __launch_bounds__(128) void sage_gemm_kernel(const float* __restrict__ h,
                                                        const float* __restrict__ msg,
                                                        const float* __restrict__ cnt,
                                                        const float* __restrict__ Wl,
                                                        const float* __restrict__ Wr,
                                                        const float* __restrict__ bias,
                                                        float* __restrict__ out) {
    __shared__ float mean_s[ROWS][D];
    __shared__ float h_s[ROWS][D];
    const int c = threadIdx.x;
    const int row0 = blockIdx.x * ROWS;

    #pragma unroll
    for (int r = 0; r < ROWS; ++r) {
        int row = row0 + r;
        float inv = 1.0f / fmaxf(cnt[row], 1.0f);
        mean_s[r][c] = msg[(size_t)row * D + c] * inv;
        h_s[r][c]    = h[(size_t)row * D + c];
    }
    __syncthreads();

    float acc[ROWS];
    const float bv = bias[c];
    #pragma unroll
    for (int r = 0; r < ROWS; ++r) acc[r] = bv;

    for (int k = 0; k < D; ++k) {
        const float wl = Wl[k * D + c];
        const float wr = Wr[k * D + c];
        #pragma unroll
        for (int r = 0; r < ROWS; ++r) {
            acc[r] = fmaf(mean_s[r][k], wl, acc[r]);
            acc[r] = fmaf(h_s[r][k],    wr, acc[r]);
        }
    }

    #pragma unroll
    for (int r = 0; r < ROWS; ++r) {
        out[(size_t)(row0 + r) * D + c] = fmaxf(acc[r], 0.0f);
    }
}

// ---------------- per-graph sum pooling (batch is sorted) ----------------
#define PNODES 32
__global__ __launch_bounds__(128) void pool_kernel(const float* __restrict__ h,
                                                   const int* __restrict__ batch,
                                                   float* __restrict__ pooled) {
    const int c = threadIdx.x;
    const int base = blockIdx.x * PNODES;
    int cur = -1;
    float acc = 0.0f;
    for (int i = 0; i < PNODES; ++i) {
        int node = base + i;
        if (node >= N_NODES) break;
        int g = batch[node];
        if (g != cur) {
            if (cur >= 0) atomicAdd(&pooled[(size_t)cur * D + c], acc);
            cur = g;
            acc = 0.0f;
        }
        acc += h[(size_t)node * D + c];
    }
    if (cur >= 0) atomicAdd(&pooled[(size_t)cur * D + c], acc);
}

// ---------------- readout: sigmoid(pooled @ Wro + bro) ----------------
__global__ __launch_bounds__(128) void final_kernel(const float* __restrict__ pooled,
                                                    const float* __restrict__ Wro,
                                                    const float* __restrict__ bro,
                                                    float* __restrict__ out) {
    const int g = blockIdx.x;
    const int c = threadIdx.x;
    float v = pooled[(size_t)g * D + c] * Wro[c];
    #pragma unroll
    for (int off = 32; off > 0; off >>= 1) v += __shfl_down(v, off, 64);
    __shared__ float partial[2];
    if ((c & 63) == 0) partial[c >> 6] = v;
    __syncthreads();
    if (c == 0) {
        float s = partial[0] + partial[1] + bro[0];
        out[g] = 1.0f / (1.0f + expf(-s));
    }
}

extern "C" void kernel_launch(void* const* d_in, const int* in_sizes, int n_in,
                              void* d_out, int out_size, void* d_ws, size_t ws_size,
                              hipStream_t stream) {
    const float* x     = (const float*)d_in[0];
    const int*   ei    = (const int*)d_in[1];
    const int*   batch = (const int*)d_in[2];
    const int*   src   = ei;              // edge_index[0]
    const int*   dst   = ei + N_EDGES;    // edge_index[1]
    const float* Wl[3] = {(const float*)d_in[3], (const float*)d_in[6], (const float*)d_in[9]};
    const float* Wr[3] = {(const float*)d_in[4], (const float*)d_in[7], (const float*)d_in[10]};
    const float* bs[3] = {(const float*)d_in[5], (const float*)d_in[8], (const float*)d_in[11]};
    const float* Wro   = (const float*)d_in[12];
    const float* bro   = (const float*)d_in[13];
    float* out = (float*)d_out;

    const size_t ND = (size_t)N_NODES * D;
    float* A      = (float*)d_ws;
    float* B      = A + ND;
    float* cnt    = B + ND;
    float* pooled = cnt + N_NODES;

    const int ZB_ND  = (int)((ND + 255) / 256);
    const int ZB_N   = (N_NODES + 255) / 256;
    const int ZB_P   = (N_GRAPHS * D + 255) / 256;
    const int SCAT_B = (N_EDGES * 32) / 256;   // 75000
    const int GEMM_B = N_NODES / ROWS;         // 12500
    const int POOL_B = N_NODES / PNODES;       // 3125

    // ---- layer 1: h = x, msg -> A, out -> A ----
    zero_kernel<<<ZB_ND, 256, 0, stream>>>(A, (int)ND);
    zero_kernel<<<ZB_N, 256, 0, stream>>>(cnt, N_NODES);
    scatter_kernel<<<SCAT_B, 256, 0, stream>>>(x, src, dst, A, cnt);
    sage_gemm_kernel<<<GEMM_B, 128, 0, stream>>>(x, A, cnt, Wl[0], Wr[0], bs[0], A);

    // ---- layer 2: h = A, msg -> B, out -> B ----
    zero_kernel<<<ZB_ND, 256, 0, stream>>>(B, (int)ND);
    zero_kernel<<<ZB_N, 256, 0, stream>>>(cnt, N_NODES);
    scatter_kernel<<<SCAT_B, 256, 0, stream>>>(A, src, dst, B, cnt);
    sage_gemm_kernel<<<GEMM_B, 128, 0, stream>>>(A, B, cnt, Wl[1], Wr[1], bs[1], B);

    // ---- layer 3: h = B, msg -> A, out -> A ----
    zero_kernel<<<ZB_ND, 256, 0, stream>>>(A, (int)ND);
    zero_kernel<<<ZB_N, 256, 0, stream>>>(cnt, N_NODES);
    scatter_kernel<<<SCAT_B, 256, 0, stream>>>(B, src, dst, A, cnt);
    sage_gemm_kernel<<<GEMM_B, 128, 0, stream>>>(B, A, cnt, Wl[2], Wr[2], bs[2], A);

    // ---- pooling + readout ----
    zero_kernel<<<ZB_P, 256, 0, stream>>>(pooled, N_GRAPHS * D);
    pool_kernel<<<POOL_B, 128, 0, stream>>>(A, batch, pooled);
    final_kernel<<<N_GRAPHS, 128, 0, stream>>>(pooled, Wro, bro, out);
}

// Round 2
// 823.579 us; speedup vs baseline: 4.6669x; 4.6669x over previous
//
#include <hip/hip_runtime.h>
#include <math.h>

#define N_NODES 100000
#define N_EDGES 600000
#define N_GRAPHS 512
#define D 128

// ---------------- zero helpers ----------------
__global__ __launch_bounds__(256) void zero_f_kernel(float* __restrict__ p, int n) {
    int i = blockIdx.x * 256 + threadIdx.x;
    if (i < n) p[i] = 0.0f;
}
__global__ __launch_bounds__(256) void zero_i_kernel(int* __restrict__ p, int n) {
    int i = blockIdx.x * 256 + threadIdx.x;
    if (i < n) p[i] = 0;
}

// ---------------- CSR build ----------------
__global__ __launch_bounds__(256) void hist_kernel(const int* __restrict__ dst,
                                                   int* __restrict__ deg) {
    int e = blockIdx.x * 256 + threadIdx.x;
    if (e < N_EDGES) atomicAdd(&deg[dst[e]], 1);
}

#define SCAN_BS 1024
// exclusive scan within blocks of SCAN_BS + per-block totals
__global__ __launch_bounds__(1024) void scan1_kernel(const int* __restrict__ deg,
                                                     int* __restrict__ excl,
                                                     int* __restrict__ blocksum) {
    __shared__ int buf[2][SCAN_BS];
    const int t = threadIdx.x;
    const int gid = blockIdx.x * SCAN_BS + t;
    int v = (gid < N_NODES) ? deg[gid] : 0;
    buf[0][t] = v;
    __syncthreads();
    int pi = 0;
    for (int off = 1; off < SCAN_BS; off <<= 1) {
        int val = buf[pi][t];
        if (t >= off) val += buf[pi][t - off];
        buf[pi ^ 1][t] = val;
        pi ^= 1;
        __syncthreads();
    }
    int incl = buf[pi][t];
    if (gid < N_NODES) excl[gid] = incl - v;
    if (t == SCAN_BS - 1) blocksum[blockIdx.x] = incl;
}

// sequential exclusive scan of block totals (98 elements — trivial)
__global__ void scan2_kernel(int* __restrict__ blocksum, int nblocks) {
    if (blockIdx.x == 0 && threadIdx.x == 0) {
        int run = 0;
        for (int i = 0; i < nblocks; ++i) {
            int v = blocksum[i];
            blocksum[i] = run;
            run += v;
        }
    }
}

__global__ __launch_bounds__(256) void scan3_kernel(const int* __restrict__ excl,
                                                    const int* __restrict__ blocksum,
                                                    int* __restrict__ rowptr) {
    int i = blockIdx.x * 256 + threadIdx.x;
    if (i < N_NODES) rowptr[i] = excl[i] + blocksum[i / SCAN_BS];
    if (i == 0) rowptr[N_NODES] = N_EDGES;
}

__global__ __launch_bounds__(256) void fill_kernel(const int* __restrict__ src,
                                                   const int* __restrict__ dst,
                                                   const int* __restrict__ rowptr,
                                                   int* __restrict__ fill,
                                                   int* __restrict__ csr_src) {
    int e = blockIdx.x * 256 + threadIdx.x;
    if (e < N_EDGES) {
        int d = dst[e];
        int pos = rowptr[d] + atomicAdd(&fill[d], 1);
        csr_src[pos] = src[e];
    }
}

// ---------------- fused gather-mean + dual GEMM + bias + relu ----------------
// out[r][c] = relu( sum_k mean[r][k]*Wl[k][c] + h[r][k]*Wr[k][c] + b[c] )
// block: 128 threads (c = threadIdx.x), ROWS rows per block.
#define ROWS 8
__global__ __launch_bounds__(128) void sage_fused_kernel(const float* __restrict__ h,
                                                         const int* __restrict__ rowptr,
                                                         const int* __restrict__ csr_src,
                                                         const float* __restrict__ Wl,
                                                         const float* __restrict__ Wr,
                                                         const float* __restrict__ bias,
                                                         float* __restrict__ out) {
    __shared__ float mean_s[ROWS][D];
    __shared__ float h_s[ROWS][D];
    const int c = threadIdx.x;
    const int row0 = blockIdx.x * ROWS;

    #pragma unroll
    for (int r = 0; r < ROWS; ++r) {
        const int row = row0 + r;
        const int beg = rowptr[row];
        const int end = rowptr[row + 1];
        float acc = 0.0f;
        for (int e = beg; e < end; ++e) {
            acc += h[(size_t)csr_src[e] * D + c];
        }
        const int deg = end - beg;
        const float inv = 1.0f / (float)max(deg, 1);
        mean_s[r][c] = acc * inv;
        h_s[r][c]    = h[(size_t)row * D + c];
    }
    __syncthreads();

    float acc[ROWS];
    const float bv = bias[c];
    #pragma unroll
    for (int r = 0; r < ROWS; ++r) acc[r] = bv;

    for (int k = 0; k < D; ++k) {
        const float wl = Wl[k * D + c];
        const float wr = Wr[k * D + c];
        #pragma unroll
        for (int r = 0; r < ROWS; ++r) {
            acc[r] = fmaf(mean_s[r][k], wl, acc[r]);
            acc[r] = fmaf(h_s[r][k],    wr, acc[r]);
        }
    }

    #pragma unroll
    for (int r = 0; r < ROWS; ++r) {
        out[(size_t)(row0 + r) * D + c] = fmaxf(acc[r], 0.0f);
    }
}

// ---------------- per-graph sum pooling (batch is sorted) ----------------
#define PNODES 32
__global__ __launch_bounds__(128) void pool_kernel(const float* __restrict__ h,
                                                   const int* __restrict__ batch,
                                                   float* __restrict__ pooled) {
    const int c = threadIdx.x;
    const int base = blockIdx.x * PNODES;
    int cur = -1;
    float acc = 0.0f;
    for (int i = 0; i < PNODES; ++i) {
        int node = base + i;
        if (node >= N_NODES) break;
        int g = batch[node];
        if (g != cur) {
            if (cur >= 0) atomicAdd(&pooled[(size_t)cur * D + c], acc);
            cur = g;
            acc = 0.0f;
        }
        acc += h[(size_t)node * D + c];
    }
    if (cur >= 0) atomicAdd(&pooled[(size_t)cur * D + c], acc);
}

// ---------------- readout: sigmoid(pooled @ Wro + bro) ----------------
__global__ __launch_bounds__(128) void final_kernel(const float* __restrict__ pooled,
                                                    const float* __restrict__ Wro,
                                                    const float* __restrict__ bro,
                                                    float* __restrict__ out) {
    const int g = blockIdx.x;
    const int c = threadIdx.x;
    float v = pooled[(size_t)g * D + c] * Wro[c];
    #pragma unroll
    for (int off = 32; off > 0; off >>= 1) v += __shfl_down(v, off, 64);
    __shared__ float partial[2];
    if ((c & 63) == 0) partial[c >> 6] = v;
    __syncthreads();
    if (c == 0) {
        float s = partial[0] + partial[1] + bro[0];
        out[g] = 1.0f / (1.0f + expf(-s));
    }
}

extern "C" void kernel_launch(void* const* d_in, const int* in_sizes, int n_in,
                              void* d_out, int out_size, void* d_ws, size_t ws_size,
                              hipStream_t stream) {
    const float* x     = (const float*)d_in[0];
    const int*   ei    = (const int*)d_in[1];
    const int*   batch = (const int*)d_in[2];
    const int*   src   = ei;              // edge_index[0]
    const int*   dst   = ei + N_EDGES;    // edge_index[1]
    const float* Wl[3] = {(const float*)d_in[3], (const float*)d_in[6], (const float*)d_in[9]};
    const float* Wr[3] = {(const float*)d_in[4], (const float*)d_in[7], (const float*)d_in[10]};
    const float* bs[3] = {(const float*)d_in[5], (const float*)d_in[8], (const float*)d_in[11]};
    const float* Wro   = (const float*)d_in[12];
    const float* bro   = (const float*)d_in[13];
    float* out = (float*)d_out;

    const size_t ND = (size_t)N_NODES * D;
    // workspace layout
    float* A      = (float*)d_ws;                   // ND floats
    float* B      = A + ND;                         // ND floats
    float* pooled = B + ND;                         // G*D floats
    int* deg      = (int*)(pooled + N_GRAPHS * D);  // N ints
    int* excl     = deg + N_NODES;                  // N ints
    int* blocksum = excl + N_NODES;                 // 128 ints
    int* rowptr   = blocksum + 128;                 // N+1 ints
    int* fill     = rowptr + N_NODES + 1;           // N ints
    int* csr_src  = fill + N_NODES;                 // E ints

    const int EB      = (N_EDGES + 255) / 256;      // 2344
    const int NB      = (N_NODES + 255) / 256;      // 391
    const int SCAN_NB = (N_NODES + SCAN_BS - 1) / SCAN_BS;  // 98
    const int ZB_P    = (N_GRAPHS * D + 255) / 256;
    const int GEMM_B  = N_NODES / ROWS;             // 12500
    const int POOL_B  = N_NODES / PNODES;           // 3125

    // ---- CSR build (once per call) ----
    zero_i_kernel<<<NB, 256, 0, stream>>>(deg, N_NODES);
    hist_kernel<<<EB, 256, 0, stream>>>(dst, deg);
    scan1_kernel<<<SCAN_NB, SCAN_BS, 0, stream>>>(deg, excl, blocksum);
    scan2_kernel<<<1, 64, 0, stream>>>(blocksum, SCAN_NB);
    scan3_kernel<<<NB, 256, 0, stream>>>(excl, blocksum, rowptr);
    zero_i_kernel<<<NB, 256, 0, stream>>>(fill, N_NODES);
    fill_kernel<<<EB, 256, 0, stream>>>(src, dst, rowptr, fill, csr_src);

    // ---- 3 fused SAGE layers ----
    sage_fused_kernel<<<GEMM_B, 128, 0, stream>>>(x, rowptr, csr_src, Wl[0], Wr[0], bs[0], A);
    sage_fused_kernel<<<GEMM_B, 128, 0, stream>>>(A, rowptr, csr_src, Wl[1], Wr[1], bs[1], B);
    sage_fused_kernel<<<GEMM_B, 128, 0, stream>>>(B, rowptr, csr_src, Wl[2], Wr[2], bs[2], A);

    // ---- pooling + readout ----
    zero_f_kernel<<<ZB_P, 256, 0, stream>>>(pooled, N_GRAPHS * D);
    pool_kernel<<<POOL_B, 128, 0, stream>>>(A, batch, pooled);
    final_kernel<<<N_GRAPHS, 128, 0, stream>>>(pooled, Wro, bro, out);
}

// Round 4
// 603.582 us; speedup vs baseline: 6.3680x; 1.3645x over previous
//
#include <hip/hip_runtime.h>
#include <math.h>

#define N_NODES 100000
#define N_EDGES 600000
#define N_GRAPHS 512
#define D 128

typedef unsigned short u16;
typedef __attribute__((ext_vector_type(8))) short short8;
typedef __attribute__((ext_vector_type(4))) float f32x4;

__device__ __forceinline__ u16 f2bf(float f) {
    unsigned int u = __float_as_uint(f);
    u += 0x7FFFu + ((u >> 16) & 1u);
    return (u16)(u >> 16);
}
__device__ __forceinline__ float bf2f(u16 h) {
    return __uint_as_float(((unsigned int)h) << 16);
}

// ---------------- zero helpers ----------------
__global__ __launch_bounds__(256) void zero_f_kernel(float* __restrict__ p, int n) {
    int i = blockIdx.x * 256 + threadIdx.x;
    if (i < n) p[i] = 0.0f;
}
__global__ __launch_bounds__(256) void zero_i_kernel(int* __restrict__ p, int n) {
    int i = blockIdx.x * 256 + threadIdx.x;
    if (i < n) p[i] = 0;
}

// ---------------- CSR build ----------------
__global__ __launch_bounds__(256) void hist_kernel(const int* __restrict__ dst,
                                                   int* __restrict__ deg) {
    int e = blockIdx.x * 256 + threadIdx.x;
    if (e < N_EDGES) atomicAdd(&deg[dst[e]], 1);
}

#define SCAN_BS 1024
__global__ __launch_bounds__(1024) void scan1_kernel(const int* __restrict__ deg,
                                                     int* __restrict__ excl,
                                                     int* __restrict__ blocksum) {
    __shared__ int buf[2][SCAN_BS];
    const int t = threadIdx.x;
    const int gid = blockIdx.x * SCAN_BS + t;
    int v = (gid < N_NODES) ? deg[gid] : 0;
    buf[0][t] = v;
    __syncthreads();
    int pi = 0;
    for (int off = 1; off < SCAN_BS; off <<= 1) {
        int val = buf[pi][t];
        if (t >= off) val += buf[pi][t - off];
        buf[pi ^ 1][t] = val;
        pi ^= 1;
        __syncthreads();
    }
    int incl = buf[pi][t];
    if (gid < N_NODES) excl[gid] = incl - v;
    if (t == SCAN_BS - 1) blocksum[blockIdx.x] = incl;
}

__global__ void scan2_kernel(int* __restrict__ blocksum, int nblocks) {
    if (blockIdx.x == 0 && threadIdx.x == 0) {
        int run = 0;
        for (int i = 0; i < nblocks; ++i) {
            int v = blocksum[i];
            blocksum[i] = run;
            run += v;
        }
    }
}

__global__ __launch_bounds__(256) void scan3_kernel(const int* __restrict__ excl,
                                                    const int* __restrict__ blocksum,
                                                    int* __restrict__ rowptr) {
    int i = blockIdx.x * 256 + threadIdx.x;
    if (i < N_NODES) rowptr[i] = excl[i] + blocksum[i / SCAN_BS];
    if (i == 0) rowptr[N_NODES] = N_EDGES;
}

__global__ __launch_bounds__(256) void fill_kernel(const int* __restrict__ src,
                                                   const int* __restrict__ dst,
                                                   const int* __restrict__ rowptr,
                                                   int* __restrict__ fill,
                                                   int* __restrict__ csr_src) {
    int e = blockIdx.x * 256 + threadIdx.x;
    if (e < N_EDGES) {
        int d = dst[e];
        int pos = rowptr[d] + atomicAdd(&fill[d], 1);
        csr_src[pos] = src[e];
    }
}

// ---------------- split x (fp32 -> bf16 hi+lo) ----------------
__global__ __launch_bounds__(256) void split_x_kernel(const float* __restrict__ x,
                                                      u16* __restrict__ hi,
                                                      u16* __restrict__ lo) {
    const int i = blockIdx.x * 256 + threadIdx.x;
    const float4 v = ((const float4*)x)[i];
    ushort4 h, l;
    h.x = f2bf(v.x); l.x = f2bf(v.x - bf2f(h.x));
    h.y = f2bf(v.y); l.y = f2bf(v.y - bf2f(h.y));
    h.z = f2bf(v.z); l.z = f2bf(v.z - bf2f(h.z));
    h.w = f2bf(v.w); l.w = f2bf(v.w - bf2f(h.w));
    ((ushort4*)hi)[i] = h;
    ((ushort4*)lo)[i] = l;
}

// ---------------- pack W' = [Wl ; Wr] (256x128) into MFMA B-fragment layout ----------------
// tile t = nt*8 + kt. lane holds 8 bf16: Wp[(t*64+lane)*8+j] = W'[kt*32+(lane>>4)*8+j][nt*16+(lane&15)]
__global__ __launch_bounds__(64) void wprep_kernel(const float* __restrict__ Wl,
                                                   const float* __restrict__ Wr,
                                                   u16* __restrict__ wph,
                                                   u16* __restrict__ wpl) {
    const int t = blockIdx.x;       // 0..63
    const int lane = threadIdx.x;   // 0..63
    const int nt = t >> 3, kt = t & 7;
    const int n = nt * 16 + (lane & 15);
    const int k0 = kt * 32 + (lane >> 4) * 8;
    #pragma unroll
    for (int j = 0; j < 8; ++j) {
        const int k = k0 + j;
        const float w = (k < 128) ? Wl[k * 128 + n] : Wr[(k - 128) * 128 + n];
        const u16 h = f2bf(w);
        wph[(t * 64 + lane) * 8 + j] = h;
        wpl[(t * 64 + lane) * 8 + j] = f2bf(w - bf2f(h));
    }
}

// ---------------- aggregation: mean of neighbor h rows -> bf16 hi/lo splits ----------------
// one wave per node, lane covers 2 columns.
__global__ __launch_bounds__(256) void agg_kernel(const u16* __restrict__ Hhi,
                                                  const u16* __restrict__ Hlo,
                                                  const int* __restrict__ rowptr,
                                                  const int* __restrict__ csr_src,
                                                  u16* __restrict__ Mhi,
                                                  u16* __restrict__ Mlo) {
    const int lane = threadIdx.x & 63;
    const int node = blockIdx.x * 4 + (threadIdx.x >> 6);
    if (node >= N_NODES) return;
    const int beg = rowptr[node];
    const int end = rowptr[node + 1];
    float ax = 0.f, ay = 0.f;
    for (int e = beg; e < end; ++e) {
        const int s = csr_src[e];
        const unsigned int vh = ((const unsigned int*)Hhi)[(size_t)s * 64 + lane];
        const unsigned int vl = ((const unsigned int*)Hlo)[(size_t)s * 64 + lane];
        ax += bf2f((u16)(vh & 0xffffu)) + bf2f((u16)(vl & 0xffffu));
        ay += bf2f((u16)(vh >> 16)) + bf2f((u16)(vl >> 16));
    }
    const float inv = 1.0f / (float)max(end - beg, 1);
    const float mx = ax * inv;
    const float my = ay * inv;
    const u16 hx = f2bf(mx), hy = f2bf(my);
    ((unsigned int*)Mhi)[(size_t)node * 64 + lane] = (unsigned int)hx | ((unsigned int)hy << 16);
    const u16 lx = f2bf(mx - bf2f(hx)), ly = f2bf(my - bf2f(hy));
    ((unsigned int*)Mlo)[(size_t)node * 64 + lane] = (unsigned int)lx | ((unsigned int)ly << 16);
}

// ---------------- MFMA GEMM: h' = relu([M | H] @ [Wl;Wr] + b) ----------------
// M=100000 (64 rows/block: 4 waves x 16), N=128, K=256. bf16x3 emulation.
// Writes h' splits in-place over (Hhi,Hlo): per-wave read-before-write, race-free.
__global__ __launch_bounds__(256) void gemm_kernel(const u16* __restrict__ Mhi,
                                                   const u16* __restrict__ Mlo,
                                                   const u16* Hhi, const u16* Hlo,
                                                   const u16* __restrict__ Wph,
                                                   const u16* __restrict__ Wpl,
                                                   const float* __restrict__ bias,
                                                   u16* OHhi, u16* OHlo) {
    const int lane = threadIdx.x & 63;
    const int wv = threadIdx.x >> 6;
    const int m0 = blockIdx.x * 64 + wv * 16;
    int rm = m0 + (lane & 15);
    if (rm >= N_NODES) rm = 0;
    const int ko = (lane >> 4) * 8;

    short8 ah[8], al[8];
    #pragma unroll
    for (int kt = 0; kt < 4; ++kt) {
        ah[kt]     = *(const short8*)(Mhi + (size_t)rm * D + kt * 32 + ko);
        al[kt]     = *(const short8*)(Mlo + (size_t)rm * D + kt * 32 + ko);
        ah[4 + kt] = *(const short8*)(Hhi + (size_t)rm * D + kt * 32 + ko);
        al[4 + kt] = *(const short8*)(Hlo + (size_t)rm * D + kt * 32 + ko);
    }

    const int rowb = m0 + ((lane >> 4) << 2);
    const int cl = lane & 15;

    #pragma unroll
    for (int nt = 0; nt < 8; ++nt) {
        f32x4 accP = {0.f, 0.f, 0.f, 0.f};
        f32x4 accQ = {0.f, 0.f, 0.f, 0.f};
        #pragma unroll
        for (int kt = 0; kt < 8; ++kt) {
            const short8 bh = *(const short8*)(Wph + (size_t)((nt * 8 + kt) * 64 + lane) * 8);
            const short8 bl = *(const short8*)(Wpl + (size_t)((nt * 8 + kt) * 64 + lane) * 8);
            accP = __builtin_amdgcn_mfma_f32_16x16x32_bf16(ah[kt], bh, accP, 0, 0, 0);
            accQ = __builtin_amdgcn_mfma_f32_16x16x32_bf16(al[kt], bh, accQ, 0, 0, 0);
            accQ = __builtin_amdgcn_mfma_f32_16x16x32_bf16(ah[kt], bl, accQ, 0, 0, 0);
        }
        const int col = nt * 16 + cl;
        const float bv = bias[col];
        #pragma unroll
        for (int r = 0; r < 4; ++r) {
            const int row = rowb + r;
            if (row < N_NODES) {
                const float v = fmaxf(accP[r] + accQ[r] + bv, 0.f);
                const u16 h = f2bf(v);
                OHhi[(size_t)row * D + col] = h;
                OHlo[(size_t)row * D + col] = f2bf(v - bf2f(h));
            }
        }
    }
}

// ---------------- per-graph sum pooling from bf16 hi/lo splits (batch sorted) ----------------
#define PNODES 32
__global__ __launch_bounds__(128) void pool_kernel(const u16* __restrict__ Hhi,
                                                   const u16* __restrict__ Hlo,
                                                   const int* __restrict__ batch,
                                                   float* __restrict__ pooled) {
    const int c = threadIdx.x;
    const int base = blockIdx.x * PNODES;
    int cur = -1;
    float acc = 0.0f;
    for (int i = 0; i < PNODES; ++i) {
        int node = base + i;
        if (node >= N_NODES) break;
        int g = batch[node];
        if (g != cur) {
            if (cur >= 0) atomicAdd(&pooled[(size_t)cur * D + c], acc);
            cur = g;
            acc = 0.0f;
        }
        acc += bf2f(Hhi[(size_t)node * D + c]) + bf2f(Hlo[(size_t)node * D + c]);
    }
    if (cur >= 0) atomicAdd(&pooled[(size_t)cur * D + c], acc);
}

// ---------------- readout: sigmoid(pooled @ Wro + bro) ----------------
__global__ __launch_bounds__(128) void final_kernel(const float* __restrict__ pooled,
                                                    const float* __restrict__ Wro,
                                                    const float* __restrict__ bro,
                                                    float* __restrict__ out) {
    const int g = blockIdx.x;
    const int c = threadIdx.x;
    float v = pooled[(size_t)g * D + c] * Wro[c];
    #pragma unroll
    for (int off = 32; off > 0; off >>= 1) v += __shfl_down(v, off, 64);
    __shared__ float partial[2];
    if ((c & 63) == 0) partial[c >> 6] = v;
    __syncthreads();
    if (c == 0) {
        float s = partial[0] + partial[1] + bro[0];
        out[g] = 1.0f / (1.0f + expf(-s));
    }
}

extern "C" void kernel_launch(void* const* d_in, const int* in_sizes, int n_in,
                              void* d_out, int out_size, void* d_ws, size_t ws_size,
                              hipStream_t stream) {
    const float* x     = (const float*)d_in[0];
    const int*   ei    = (const int*)d_in[1];
    const int*   batch = (const int*)d_in[2];
    const int*   src   = ei;
    const int*   dst   = ei + N_EDGES;
    const float* Wl[3] = {(const float*)d_in[3], (const float*)d_in[6], (const float*)d_in[9]};
    const float* Wr[3] = {(const float*)d_in[4], (const float*)d_in[7], (const float*)d_in[10]};
    const float* bs[3] = {(const float*)d_in[5], (const float*)d_in[8], (const float*)d_in[11]};
    const float* Wro   = (const float*)d_in[12];
    const float* bro   = (const float*)d_in[13];
    float* out = (float*)d_out;

    const size_t ND = (size_t)N_NODES * D;
    char* ws = (char*)d_ws;
    u16* Hhi = (u16*)ws;                       // ND u16
    u16* Hlo = Hhi + ND;                       // ND u16
    u16* Mhi = Hlo + ND;                       // ND u16
    u16* Mlo = Mhi + ND;                       // ND u16
    float* pooled = (float*)(Mlo + ND);        // G*D f32
    u16* Wph = (u16*)(pooled + (size_t)N_GRAPHS * D);  // 3*32768 u16
    u16* Wpl = Wph + 3 * 32768;                        // 3*32768 u16
    int* deg      = (int*)(Wpl + 3 * 32768);
    int* excl     = deg + N_NODES;
    int* blocksum = excl + N_NODES;            // 128
    int* rowptr   = blocksum + 128;            // N+1
    int* fill     = rowptr + N_NODES + 1;
    int* csr_src  = fill + N_NODES;            // E

    const int EB      = (N_EDGES + 255) / 256;
    const int NB      = (N_NODES + 255) / 256;
    const int SCAN_NB = (N_NODES + SCAN_BS - 1) / SCAN_BS;
    const int ZB_P    = (N_GRAPHS * D + 255) / 256;
    const int SPLIT_B = (int)(ND / 4 / 256);          // 12500
    const int AGG_B   = N_NODES / 4;                  // 25000
    const int GEMM_B  = (N_NODES + 63) / 64;          // 1563
    const int POOL_B  = N_NODES / PNODES;             // 3125

    // ---- CSR build ----
    zero_i_kernel<<<NB, 256, 0, stream>>>(deg, N_NODES);
    hist_kernel<<<EB, 256, 0, stream>>>(dst, deg);
    scan1_kernel<<<SCAN_NB, SCAN_BS, 0, stream>>>(deg, excl, blocksum);
    scan2_kernel<<<1, 64, 0, stream>>>(blocksum, SCAN_NB);
    scan3_kernel<<<NB, 256, 0, stream>>>(excl, blocksum, rowptr);
    zero_i_kernel<<<NB, 256, 0, stream>>>(fill, N_NODES);
    fill_kernel<<<EB, 256, 0, stream>>>(src, dst, rowptr, fill, csr_src);

    // ---- prep: split x, pack weights ----
    split_x_kernel<<<SPLIT_B, 256, 0, stream>>>(x, Hhi, Hlo);
    for (int l = 0; l < 3; ++l)
        wprep_kernel<<<64, 64, 0, stream>>>(Wl[l], Wr[l], Wph + l * 32768, Wpl + l * 32768);

    // ---- 3 layers: aggregate-then-GEMM (h splits updated in place) ----
    for (int l = 0; l < 3; ++l) {
        agg_kernel<<<AGG_B, 256, 0, stream>>>(Hhi, Hlo, rowptr, csr_src, Mhi, Mlo);
        gemm_kernel<<<GEMM_B, 256, 0, stream>>>(Mhi, Mlo, Hhi, Hlo,
                                                Wph + l * 32768, Wpl + l * 32768, bs[l],
                                                Hhi, Hlo);
    }

    // ---- pooling + readout ----
    zero_f_kernel<<<ZB_P, 256, 0, stream>>>(pooled, N_GRAPHS * D);
    pool_kernel<<<POOL_B, 128, 0, stream>>>(Hhi, Hlo, batch, pooled);
    final_kernel<<<N_GRAPHS, 128, 0, stream>>>(pooled, Wro, bro, out);
}

// Round 5
// 513.103 us; speedup vs baseline: 7.4909x; 1.1763x over previous
//
#include <hip/hip_runtime.h>
#include <math.h>

#define N_NODES 100000
#define N_EDGES 600000
#define N_GRAPHS 512
#define D 128

typedef unsigned short u16;
typedef __attribute__((ext_vector_type(8))) short short8;
typedef __attribute__((ext_vector_type(4))) float f32x4;
typedef __attribute__((ext_vector_type(4))) unsigned int u32x4;

__device__ __forceinline__ u16 f2bf(float f) {
    unsigned int u = __float_as_uint(f);
    u += 0x7FFFu + ((u >> 16) & 1u);
    return (u16)(u >> 16);
}
__device__ __forceinline__ float bf2f(u16 h) {
    return __uint_as_float(((unsigned int)h) << 16);
}
// packed element: hi bf16 in top 16 bits, lo bf16 in low 16 bits
__device__ __forceinline__ unsigned int packsplit(float v) {
    unsigned int u = __float_as_uint(v);
    unsigned int hi = (u + (0x7FFFu + ((u >> 16) & 1u))) & 0xffff0000u;
    float lo = v - __uint_as_float(hi);
    unsigned int ul = __float_as_uint(lo);
    unsigned int l16 = (ul + (0x7FFFu + ((ul >> 16) & 1u))) >> 16;
    return hi | l16;
}
__device__ __forceinline__ float hi_f(unsigned int w) { return __uint_as_float(w & 0xffff0000u); }
__device__ __forceinline__ float lo_f(unsigned int w) { return __uint_as_float(w << 16); }
__device__ __forceinline__ float unpack_sum(unsigned int w) { return hi_f(w) + lo_f(w); }

// ---------------- zero helpers ----------------
__global__ __launch_bounds__(256) void zero_f_kernel(float* __restrict__ p, int n) {
    int i = blockIdx.x * 256 + threadIdx.x;
    if (i < n) p[i] = 0.0f;
}
__global__ __launch_bounds__(256) void zero_i_kernel(int* __restrict__ p, int n) {
    int i = blockIdx.x * 256 + threadIdx.x;
    if (i < n) p[i] = 0;
}

// ---------------- CSR build ----------------
__global__ __launch_bounds__(256) void hist_kernel(const int* __restrict__ dst,
                                                   int* __restrict__ deg) {
    int e = blockIdx.x * 256 + threadIdx.x;
    if (e < N_EDGES) atomicAdd(&deg[dst[e]], 1);
}

#define SCAN_BS 1024
__global__ __launch_bounds__(1024) void scan1_kernel(const int* __restrict__ deg,
                                                     int* __restrict__ excl,
                                                     int* __restrict__ blocksum) {
    __shared__ int buf[2][SCAN_BS];
    const int t = threadIdx.x;
    const int gid = blockIdx.x * SCAN_BS + t;
    int v = (gid < N_NODES) ? deg[gid] : 0;
    buf[0][t] = v;
    __syncthreads();
    int pi = 0;
    for (int off = 1; off < SCAN_BS; off <<= 1) {
        int val = buf[pi][t];
        if (t >= off) val += buf[pi][t - off];
        buf[pi ^ 1][t] = val;
        pi ^= 1;
        __syncthreads();
    }
    int incl = buf[pi][t];
    if (gid < N_NODES) excl[gid] = incl - v;
    if (t == SCAN_BS - 1) blocksum[blockIdx.x] = incl;
}

// parallel exclusive scan of block totals (<=128 elements), one block
__global__ __launch_bounds__(128) void scan2_kernel(int* __restrict__ blocksum, int n) {
    __shared__ int buf[2][128];
    const int t = threadIdx.x;
    int v = (t < n) ? blocksum[t] : 0;
    buf[0][t] = v;
    __syncthreads();
    int pi = 0;
    for (int off = 1; off < 128; off <<= 1) {
        int val = buf[pi][t];
        if (t >= off) val += buf[pi][t - off];
        buf[pi ^ 1][t] = val;
        pi ^= 1;
        __syncthreads();
    }
    if (t < n) blocksum[t] = buf[pi][t] - v;
}

__global__ __launch_bounds__(256) void scan3_kernel(const int* __restrict__ excl,
                                                    const int* __restrict__ blocksum,
                                                    int* __restrict__ rowptr) {
    int i = blockIdx.x * 256 + threadIdx.x;
    if (i < N_NODES) rowptr[i] = excl[i] + blocksum[i / SCAN_BS];
    if (i == 0) rowptr[N_NODES] = N_EDGES;
}

__global__ __launch_bounds__(256) void fill_kernel(const int* __restrict__ src,
                                                   const int* __restrict__ dst,
                                                   const int* __restrict__ rowptr,
                                                   int* __restrict__ fill,
                                                   int* __restrict__ csr_src) {
    int e = blockIdx.x * 256 + threadIdx.x;
    if (e < N_EDGES) {
        int d = dst[e];
        int pos = rowptr[d] + atomicAdd(&fill[d], 1);
        csr_src[pos] = src[e];
    }
}

// ---------------- split x (fp32 -> packed hi/lo u32) ----------------
__global__ __launch_bounds__(256) void split_x_kernel(const float* __restrict__ x,
                                                      unsigned int* __restrict__ Hx) {
    const int i = blockIdx.x * 256 + threadIdx.x;
    const float4 v = ((const float4*)x)[i];
    uint4 w;
    w.x = packsplit(v.x);
    w.y = packsplit(v.y);
    w.z = packsplit(v.z);
    w.w = packsplit(v.w);
    ((uint4*)Hx)[i] = w;
}

// ---------------- pack W' = [Wl ; Wr] (256x128) into MFMA B-fragment layout ----------------
// one launch, 3 layers x 64 tiles. tile t = nt*8+kt.
// Wp[(t*64+lane)*8+j] = W'[kt*32+(lane>>4)*8+j][nt*16+(lane&15)]
__global__ __launch_bounds__(64) void wprep_kernel(const float* __restrict__ Wl1, const float* __restrict__ Wr1,
                                                   const float* __restrict__ Wl2, const float* __restrict__ Wr2,
                                                   const float* __restrict__ Wl3, const float* __restrict__ Wr3,
                                                   u16* __restrict__ wph, u16* __restrict__ wpl) {
    const int layer = blockIdx.x >> 6;
    const int t = blockIdx.x & 63;
    const int lane = threadIdx.x;
    const float* Wl = (layer == 0) ? Wl1 : (layer == 1) ? Wl2 : Wl3;
    const float* Wr = (layer == 0) ? Wr1 : (layer == 1) ? Wr2 : Wr3;
    const int nt = t >> 3, kt = t & 7;
    const int n = nt * 16 + (lane & 15);
    const int k0 = kt * 32 + (lane >> 4) * 8;
    const size_t base = (size_t)layer * 32768 + (size_t)(t * 64 + lane) * 8;
    #pragma unroll
    for (int j = 0; j < 8; ++j) {
        const int k = k0 + j;
        const float w = (k < 128) ? Wl[k * 128 + n] : Wr[(k - 128) * 128 + n];
        const u16 h = f2bf(w);
        wph[base + j] = h;
        wpl[base + j] = f2bf(w - bf2f(h));
    }
}

// ---------------- aggregation: mean of neighbor rows (packed) ----------------
// one wave per node, lane covers 2 columns. csr indices loaded cooperatively,
// broadcast via shfl; 4 independent row loads in flight per iteration.
__global__ __launch_bounds__(256) void agg_kernel(const unsigned int* __restrict__ Hx,
                                                  const int* __restrict__ rowptr,
                                                  const int* __restrict__ csr_src,
                                                  unsigned int* __restrict__ Mx) {
    const int lane = threadIdx.x & 63;
    const int node = blockIdx.x * 4 + (threadIdx.x >> 6);
    if (node >= N_NODES) return;
    const int beg = rowptr[node];
    const int end = rowptr[node + 1];
    float a0 = 0.f, a1 = 0.f;
    const int co = lane * 2;
    for (int c0 = beg; c0 < end; c0 += 64) {
        const int nv = min(64, end - c0);
        int msrc = (c0 + lane < end) ? csr_src[c0 + lane] : 0;
        int j = 0;
        for (; j + 4 <= nv; j += 4) {
            const int s0 = __shfl(msrc, j + 0);
            const int s1 = __shfl(msrc, j + 1);
            const int s2 = __shfl(msrc, j + 2);
            const int s3 = __shfl(msrc, j + 3);
            const uint2 w0 = *(const uint2*)(Hx + (size_t)s0 * D + co);
            const uint2 w1 = *(const uint2*)(Hx + (size_t)s1 * D + co);
            const uint2 w2 = *(const uint2*)(Hx + (size_t)s2 * D + co);
            const uint2 w3 = *(const uint2*)(Hx + (size_t)s3 * D + co);
            a0 += unpack_sum(w0.x) + unpack_sum(w1.x) + unpack_sum(w2.x) + unpack_sum(w3.x);
            a1 += unpack_sum(w0.y) + unpack_sum(w1.y) + unpack_sum(w2.y) + unpack_sum(w3.y);
        }
        for (; j < nv; ++j) {
            const int s = __shfl(msrc, j);
            const uint2 w = *(const uint2*)(Hx + (size_t)s * D + co);
            a0 += unpack_sum(w.x);
            a1 += unpack_sum(w.y);
        }
    }
    const float inv = 1.0f / (float)max(end - beg, 1);
    uint2 o;
    o.x = packsplit(a0 * inv);
    o.y = packsplit(a1 * inv);
    *(uint2*)(Mx + (size_t)node * D + co) = o;
}

// ---------------- MFMA GEMM: h' = relu([M | H] @ [Wl;Wr] + b) ----------------
// 64 rows/block (4 waves x 16), N=128, K=256, bf16x3 emulation.
// A read from packed u32 buffers (unpacked in-register); h' written packed
// in place over Hx (per-wave read-before-write, block-local rows: race-free).
__global__ __launch_bounds__(256) void gemm_kernel(const unsigned int* __restrict__ Mx,
                                                   const unsigned int* Hx,
                                                   const u16* __restrict__ Wph,
                                                   const u16* __restrict__ Wpl,
                                                   const float* __restrict__ bias,
                                                   unsigned int* OHx) {
    const int lane = threadIdx.x & 63;
    const int wv = threadIdx.x >> 6;
    const int m0 = blockIdx.x * 64 + wv * 16;
    int rm = m0 + (lane & 15);
    if (rm >= N_NODES) rm = 0;
    const int ko = (lane >> 4) * 8;

    short8 ah[8], al[8];
    #pragma unroll
    for (int kt = 0; kt < 4; ++kt) {
        #pragma unroll
        for (int half = 0; half < 2; ++half) {
            const unsigned int* base = (half == 0) ? (Mx + (size_t)rm * D + kt * 32 + ko)
                                                   : (Hx + (size_t)rm * D + kt * 32 + ko);
            const u32x4 p = *(const u32x4*)(base);
            const u32x4 q = *(const u32x4*)(base + 4);
            u32x4 hv, lv;
            hv.x = (p.x >> 16) | (p.y & 0xffff0000u);
            hv.y = (p.z >> 16) | (p.w & 0xffff0000u);
            hv.z = (q.x >> 16) | (q.y & 0xffff0000u);
            hv.w = (q.z >> 16) | (q.w & 0xffff0000u);
            lv.x = (p.x & 0xffffu) | (p.y << 16);
            lv.y = (p.z & 0xffffu) | (p.w << 16);
            lv.z = (q.x & 0xffffu) | (q.y << 16);
            lv.w = (q.z & 0xffffu) | (q.w << 16);
            ah[half * 4 + kt] = __builtin_bit_cast(short8, hv);
            al[half * 4 + kt] = __builtin_bit_cast(short8, lv);
        }
    }

    const int rowb = m0 + ((lane >> 4) << 2);
    const int cl = lane & 15;

    #pragma unroll
    for (int nt = 0; nt < 8; ++nt) {
        f32x4 accP = {0.f, 0.f, 0.f, 0.f};
        f32x4 accQ = {0.f, 0.f, 0.f, 0.f};
        #pragma unroll
        for (int kt = 0; kt < 8; ++kt) {
            const short8 bh = *(const short8*)(Wph + (size_t)((nt * 8 + kt) * 64 + lane) * 8);
            const short8 bl = *(const short8*)(Wpl + (size_t)((nt * 8 + kt) * 64 + lane) * 8);
            accP = __builtin_amdgcn_mfma_f32_16x16x32_bf16(ah[kt], bh, accP, 0, 0, 0);
            accQ = __builtin_amdgcn_mfma_f32_16x16x32_bf16(al[kt], bh, accQ, 0, 0, 0);
            accQ = __builtin_amdgcn_mfma_f32_16x16x32_bf16(ah[kt], bl, accQ, 0, 0, 0);
        }
        const int col = nt * 16 + cl;
        const float bv = bias[col];
        #pragma unroll
        for (int r = 0; r < 4; ++r) {
            const int row = rowb + r;
            if (row < N_NODES) {
                const float v = fmaxf(accP[r] + accQ[r] + bv, 0.f);
                OHx[(size_t)row * D + col] = packsplit(v);
            }
        }
    }
}

// ---------------- per-graph sum pooling from packed h (batch sorted) ----------------
#define PNODES 32
__global__ __launch_bounds__(128) void pool_kernel(const unsigned int* __restrict__ Hx,
                                                   const int* __restrict__ batch,
                                                   float* __restrict__ pooled) {
    const int c = threadIdx.x;
    const int base = blockIdx.x * PNODES;
    int cur = -1;
    float acc = 0.0f;
    for (int i = 0; i < PNODES; ++i) {
        int node = base + i;
        if (node >= N_NODES) break;
        int g = batch[node];
        if (g != cur) {
            if (cur >= 0) atomicAdd(&pooled[(size_t)cur * D + c], acc);
            cur = g;
            acc = 0.0f;
        }
        acc += unpack_sum(Hx[(size_t)node * D + c]);
    }
    if (cur >= 0) atomicAdd(&pooled[(size_t)cur * D + c], acc);
}

// ---------------- readout: sigmoid(pooled @ Wro + bro) ----------------
__global__ __launch_bounds__(128) void final_kernel(const float* __restrict__ pooled,
                                                    const float* __restrict__ Wro,
                                                    const float* __restrict__ bro,
                                                    float* __restrict__ out) {
    const int g = blockIdx.x;
    const int c = threadIdx.x;
    float v = pooled[(size_t)g * D + c] * Wro[c];
    #pragma unroll
    for (int off = 32; off > 0; off >>= 1) v += __shfl_down(v, off, 64);
    __shared__ float partial[2];
    if ((c & 63) == 0) partial[c >> 6] = v;
    __syncthreads();
    if (c == 0) {
        float s = partial[0] + partial[1] + bro[0];
        out[g] = 1.0f / (1.0f + expf(-s));
    }
}

extern "C" void kernel_launch(void* const* d_in, const int* in_sizes, int n_in,
                              void* d_out, int out_size, void* d_ws, size_t ws_size,
                              hipStream_t stream) {
    const float* x     = (const float*)d_in[0];
    const int*   ei    = (const int*)d_in[1];
    const int*   batch = (const int*)d_in[2];
    const int*   src   = ei;
    const int*   dst   = ei + N_EDGES;
    const float* Wl[3] = {(const float*)d_in[3], (const float*)d_in[6], (const float*)d_in[9]};
    const float* Wr[3] = {(const float*)d_in[4], (const float*)d_in[7], (const float*)d_in[10]};
    const float* bs[3] = {(const float*)d_in[5], (const float*)d_in[8], (const float*)d_in[11]};
    const float* Wro   = (const float*)d_in[12];
    const float* bro   = (const float*)d_in[13];
    float* out = (float*)d_out;

    const size_t ND = (size_t)N_NODES * D;
    char* ws = (char*)d_ws;
    unsigned int* Hx = (unsigned int*)ws;          // ND u32 (packed hi/lo)
    unsigned int* Mx = Hx + ND;                    // ND u32
    float* pooled = (float*)(Mx + ND);             // G*D f32
    u16* Wph = (u16*)(pooled + (size_t)N_GRAPHS * D);  // 3*32768 u16
    u16* Wpl = Wph + 3 * 32768;                        // 3*32768 u16
    int* deg      = (int*)(Wpl + 3 * 32768);       // N (deg, fill adjacent for fused zero)
    int* fill     = deg + N_NODES;                 // N
    int* excl     = fill + N_NODES;                // N
    int* blocksum = excl + N_NODES;                // 128
    int* rowptr   = blocksum + 128;                // N+1
    int* csr_src  = rowptr + N_NODES + 1;          // E

    const int EB      = (N_EDGES + 255) / 256;
    const int NB      = (N_NODES + 255) / 256;
    const int NB2     = (2 * N_NODES + 255) / 256;
    const int SCAN_NB = (N_NODES + SCAN_BS - 1) / SCAN_BS;   // 98
    const int ZB_P    = (N_GRAPHS * D + 255) / 256;
    const int SPLIT_B = (int)(ND / 4 / 256);                 // 12500
    const int AGG_B   = N_NODES / 4;                         // 25000
    const int GEMM_B  = (N_NODES + 63) / 64;                 // 1563
    const int POOL_B  = N_NODES / PNODES;                    // 3125

    // ---- CSR build ----
    zero_i_kernel<<<NB2, 256, 0, stream>>>(deg, 2 * N_NODES);   // deg + fill
    hist_kernel<<<EB, 256, 0, stream>>>(dst, deg);
    scan1_kernel<<<SCAN_NB, SCAN_BS, 0, stream>>>(deg, excl, blocksum);
    scan2_kernel<<<1, 128, 0, stream>>>(blocksum, SCAN_NB);
    scan3_kernel<<<NB, 256, 0, stream>>>(excl, blocksum, rowptr);
    fill_kernel<<<EB, 256, 0, stream>>>(src, dst, rowptr, fill, csr_src);

    // ---- prep: split x, pack weights (single launch) ----
    split_x_kernel<<<SPLIT_B, 256, 0, stream>>>(x, Hx);
    wprep_kernel<<<192, 64, 0, stream>>>(Wl[0], Wr[0], Wl[1], Wr[1], Wl[2], Wr[2], Wph, Wpl);

    // ---- 3 layers: aggregate-then-GEMM (h packed, updated in place) ----
    for (int l = 0; l < 3; ++l) {
        agg_kernel<<<AGG_B, 256, 0, stream>>>(Hx, rowptr, csr_src, Mx);
        gemm_kernel<<<GEMM_B, 256, 0, stream>>>(Mx, Hx,
                                                Wph + l * 32768, Wpl + l * 32768, bs[l],
                                                Hx);
    }

    // ---- pooling + readout ----
    zero_f_kernel<<<ZB_P, 256, 0, stream>>>(pooled, N_GRAPHS * D);
    pool_kernel<<<POOL_B, 128, 0, stream>>>(Hx, batch, pooled);
    final_kernel<<<N_GRAPHS, 128, 0, stream>>>(pooled, Wro, bro, out);
}